// Round 4
// baseline (317.682 us; speedup 1.0000x reference)
//
#include <hip/hip_runtime.h>

typedef float f32x4 __attribute__((ext_vector_type(4)));
typedef short bf16x8 __attribute__((ext_vector_type(8)));

// ---------- bf16 helpers (manual RNE, verified rounds 2-3) ----------
__device__ __forceinline__ unsigned short f2bf(float f) {
    union { float f; unsigned int i; } x;
    x.f = f;
    unsigned int i = x.i;
    unsigned int lsb = (i >> 16) & 1u;
    i += 0x7FFFu + lsb;
    return (unsigned short)(i >> 16);
}
__device__ __forceinline__ bf16x8 cvt8(float4 a, float4 b) {
    union { bf16x8 v; unsigned short u[8]; } r;
    r.u[0] = f2bf(a.x); r.u[1] = f2bf(a.y); r.u[2] = f2bf(a.z); r.u[3] = f2bf(a.w);
    r.u[4] = f2bf(b.x); r.u[5] = f2bf(b.y); r.u[6] = f2bf(b.z); r.u[7] = f2bf(b.w);
    return r.v;
}

// ws layout (bytes):
//   0        : WqkvT bf16 [768][256]   (393216 B)
//   393216   : WoutT bf16 [256][256]   (131072 B)
//   524288   : bias_tab f32 [64][64]   (16384 B)
#define WS_NEED 540672
#define WOUTT_SHORT_OFF 196608

// =====================================================================
// Prep: transpose weights to bf16 n-major; expand PE to [q][j] table.
// grid 257 x 256.
// =====================================================================
__global__ void prep_kernel(const float* __restrict__ wqkv,
                            const float* __restrict__ wout,
                            const float* __restrict__ pe,
                            unsigned short* __restrict__ wsT,
                            float* __restrict__ bias_tab)
{
    const int b = blockIdx.x, tid = threadIdx.x;
    if (b < 256) {
        const int w = tid >> 6, l = tid & 63;
        const int r = b * 4 + w;               // output row (n)
        const float* src;
        unsigned short* dst;
        int stride;
        if (r < 768) { src = wqkv + r; stride = 768; dst = wsT + (size_t)r * 256; }
        else { int n = r - 768; src = wout + n; stride = 256;
               dst = wsT + WOUTT_SHORT_OFF + (size_t)n * 256; }
        ushort4 v;
        v.x = f2bf(src[(size_t)(l * 4 + 0) * stride]);
        v.y = f2bf(src[(size_t)(l * 4 + 1) * stride]);
        v.z = f2bf(src[(size_t)(l * 4 + 2) * stride]);
        v.w = f2bf(src[(size_t)(l * 4 + 3) * stride]);
        *reinterpret_cast<ushort4*>(dst + l * 4) = v;
    } else {
        #pragma unroll
        for (int i = 0; i < 16; ++i) {
            int idx = tid + i * 256;           // q*64 + j
            int q = idx >> 6, j = idx & 63;
            int dy = (j >> 3) - (q >> 3) + 7;
            int dx = (j & 7) - (q & 7) + 7;
            bias_tab[idx] = pe[dy * 15 + dx];
        }
    }
}

// =====================================================================
// winattn2: 2 heads per block, grid 4096, 256 threads (4 waves).
// No X/W LDS staging: A-frags direct f32 global + cvt, B-frags direct
// bf16 from prepped W^T. LDS only Q/K/V^T/P (38.9 KB) -> 4 blocks/CU.
// =====================================================================
__global__ __launch_bounds__(256, 4)
void winattn2(const float* __restrict__ x,
              const unsigned short* __restrict__ wqkvT,
              const float* __restrict__ bias_tab,
              float* __restrict__ out)
{
    __shared__ __align__(16) unsigned short sQ[2][64][40];
    __shared__ __align__(16) unsigned short sK[2][64][40];
    __shared__ __align__(16) unsigned short sVT[2][32][72];
    __shared__ __align__(16) unsigned short sP[4][16][72];

    const int tid  = threadIdx.x;
    const int lane = tid & 63;
    const int wv   = tid >> 6;
    const int ln   = lane & 15;
    const int lg   = lane >> 4;

    // XCD swizzle: the 4 blocks of one window land on the same XCD
    const int L   = ((blockIdx.x & 7) << 9) + (blockIdx.x >> 3);
    const int wid = L >> 2;
    const int h0  = (L & 3) << 1;          // head pair h0, h0+1
    const int blw = wid >> 6;
    const int whr = (wid >> 3) & 7;
    const int wwc = wid & 7;
    const int tok_base = blw * 4096 + whr * 512 + wwc * 8;

    // ---- QKV GEMM: A direct from x (f32), B direct from WqkvT ----
    const int arow = wv * 16 + ln;
    const int atok = tok_base + ((arow >> 3) << 6) + (arow & 7);
    const float* xbase = x + (size_t)atok * 256 + lg * 8;

    f32x4 acc[12];
    #pragma unroll
    for (int i = 0; i < 12; ++i) acc[i] = (f32x4)(0.f);

    #pragma unroll
    for (int kst = 0; kst < 8; ++kst) {
        float4 xa = *reinterpret_cast<const float4*>(xbase + kst * 32);
        float4 xb = *reinterpret_cast<const float4*>(xbase + kst * 32 + 4);
        bf16x8 af = cvt8(xa, xb);
        #pragma unroll
        for (int hp = 0; hp < 2; ++hp) {
            #pragma unroll
            for (int j = 0; j < 6; ++j) {
                int n = (j >> 1) * 256 + (h0 + hp) * 32 + (j & 1) * 16 + ln;
                bf16x8 bf = *reinterpret_cast<const bf16x8*>(
                    wqkvT + (size_t)n * 256 + kst * 32 + lg * 8);
                acc[hp * 6 + j] =
                    __builtin_amdgcn_mfma_f32_16x16x32_bf16(af, bf, acc[hp * 6 + j], 0, 0, 0);
            }
        }
    }

    // ---- epilogue: Q(scaled),K -> [tok][ch]; V -> V^T[ch][tok] ----
    const float scale = 0.17677669529663687f;
    #pragma unroll
    for (int hp = 0; hp < 2; ++hp) {
        #pragma unroll
        for (int j = 0; j < 2; ++j)
            #pragma unroll
            for (int r = 0; r < 4; ++r)
                sQ[hp][wv * 16 + lg * 4 + r][j * 16 + ln] = f2bf(acc[hp * 6 + j][r] * scale);
        #pragma unroll
        for (int j = 2; j < 4; ++j)
            #pragma unroll
            for (int r = 0; r < 4; ++r)
                sK[hp][wv * 16 + lg * 4 + r][(j - 2) * 16 + ln] = f2bf(acc[hp * 6 + j][r]);
        #pragma unroll
        for (int j = 4; j < 6; ++j) {
            ushort4 pv;
            pv.x = f2bf(acc[hp * 6 + j][0]); pv.y = f2bf(acc[hp * 6 + j][1]);
            pv.z = f2bf(acc[hp * 6 + j][2]); pv.w = f2bf(acc[hp * 6 + j][3]);
            *reinterpret_cast<ushort4*>(&sVT[hp][(j - 4) * 16 + ln][wv * 16 + lg * 4]) = pv;
        }
    }
    __syncthreads();

    // ---- attention: wave wv owns q-tile wv, loops over both heads ----
    const int q = wv * 16 + ln;
    #pragma unroll
    for (int hp = 0; hp < 2; ++hp) {
        bf16x8 qf = *reinterpret_cast<const bf16x8*>(&sQ[hp][q][lg * 8]);
        f32x4 st[4];
        #pragma unroll
        for (int mt = 0; mt < 4; ++mt) {
            bf16x8 kf = *reinterpret_cast<const bf16x8*>(&sK[hp][mt * 16 + ln][lg * 8]);
            st[mt] = __builtin_amdgcn_mfma_f32_16x16x32_bf16(kf, qf, (f32x4)(0.f), 0, 0, 0);
        }

        float sv[16];
        float mx = -3.0e38f;
        #pragma unroll
        for (int mt = 0; mt < 4; ++mt) {
            float4 bt = *reinterpret_cast<const float4*>(
                &bias_tab[q * 64 + mt * 16 + lg * 4]);
            float b4[4] = {bt.x, bt.y, bt.z, bt.w};
            #pragma unroll
            for (int r = 0; r < 4; ++r) {
                float s = st[mt][r] + b4[r];
                sv[mt * 4 + r] = s;
                mx = fmaxf(mx, s);
            }
        }
        mx = fmaxf(mx, __shfl_xor(mx, 16));
        mx = fmaxf(mx, __shfl_xor(mx, 32));
        float sum = 0.f;
        #pragma unroll
        for (int i = 0; i < 16; ++i) { sv[i] = __expf(sv[i] - mx); sum += sv[i]; }
        sum += __shfl_xor(sum, 16);
        sum += __shfl_xor(sum, 32);
        const float inv = 1.0f / sum;

        #pragma unroll
        for (int mt = 0; mt < 4; ++mt) {
            ushort4 pv;
            pv.x = f2bf(sv[mt * 4 + 0] * inv);
            pv.y = f2bf(sv[mt * 4 + 1] * inv);
            pv.z = f2bf(sv[mt * 4 + 2] * inv);
            pv.w = f2bf(sv[mt * 4 + 3] * inv);
            *reinterpret_cast<ushort4*>(&sP[wv][ln][mt * 16 + lg * 4]) = pv;
        }

        f32x4 o[2] = {(f32x4)(0.f), (f32x4)(0.f)};
        #pragma unroll
        for (int ks = 0; ks < 2; ++ks) {
            bf16x8 pf = *reinterpret_cast<const bf16x8*>(&sP[wv][ln][ks * 32 + lg * 8]);
            #pragma unroll
            for (int nt = 0; nt < 2; ++nt) {
                bf16x8 vf = *reinterpret_cast<const bf16x8*>(
                    &sVT[hp][nt * 16 + ln][ks * 32 + lg * 8]);
                o[nt] = __builtin_amdgcn_mfma_f32_16x16x32_bf16(pf, vf, o[nt], 0, 0, 0);
            }
        }

        #pragma unroll
        for (int nt = 0; nt < 2; ++nt) {
            #pragma unroll
            for (int r = 0; r < 4; ++r) {
                int qi  = wv * 16 + lg * 4 + r;
                int tok = tok_base + ((qi >> 3) << 6) + (qi & 7);
                out[(size_t)tok * 256 + (h0 + hp) * 32 + nt * 16 + ln] = o[nt][r];
            }
        }
    }
}

// =====================================================================
// proj2: in-place out = A @ w_out + b_out, no LDS. grid 1024 x 256.
// A-frags direct f32 (L3-resident), B-frags from prepped WoutT.
// =====================================================================
__global__ __launch_bounds__(256, 4)
void proj2(float* __restrict__ io,
           const unsigned short* __restrict__ woutT,
           const float* __restrict__ b_out)
{
    const int tid  = threadIdx.x;
    const int lane = tid & 63;
    const int wv   = tid >> 6;
    const int ln   = lane & 15;
    const int lg   = lane >> 4;
    const size_t m0 = (size_t)blockIdx.x * 64;

    const float* abase = io + (m0 + wv * 16 + ln) * 256 + lg * 8;

    f32x4 acc[16];
    #pragma unroll
    for (int nt = 0; nt < 16; ++nt) acc[nt] = (f32x4)(0.f);

    #pragma unroll
    for (int kst = 0; kst < 8; ++kst) {
        float4 xa = *reinterpret_cast<const float4*>(abase + kst * 32);
        float4 xb = *reinterpret_cast<const float4*>(abase + kst * 32 + 4);
        bf16x8 af = cvt8(xa, xb);
        #pragma unroll
        for (int nt = 0; nt < 16; ++nt) {
            bf16x8 bf = *reinterpret_cast<const bf16x8*>(
                woutT + (size_t)(nt * 16 + ln) * 256 + kst * 32 + lg * 8);
            acc[nt] = __builtin_amdgcn_mfma_f32_16x16x32_bf16(af, bf, acc[nt], 0, 0, 0);
        }
    }

    // drain all in-flight reads of io before the in-place overwrite
    asm volatile("s_waitcnt vmcnt(0)" ::: "memory");

    #pragma unroll
    for (int nt = 0; nt < 16; ++nt) {
        float bias = b_out[nt * 16 + ln];
        #pragma unroll
        for (int r = 0; r < 4; ++r)
            io[(m0 + wv * 16 + lg * 4 + r) * 256 + nt * 16 + ln] = acc[nt][r] + bias;
    }
}

// =====================================================================
// Fallback (round-3 verified kernels) if ws_size < WS_NEED.
// =====================================================================
__device__ __forceinline__ bf16x8 ldsFrag(const unsigned short* p) {
    return *reinterpret_cast<const bf16x8*>(p);
}

__global__ __launch_bounds__(256, 2)
void winattn_fb(const float* __restrict__ x,
                const float* __restrict__ w_qkv,
                const float* __restrict__ pe,
                float* __restrict__ attn_out)
{
    __shared__ __align__(16) unsigned short sX[64][264];
    __shared__ __align__(16) unsigned short sW[96][72];
    __shared__ __align__(16) unsigned short sQ[64][40];
    __shared__ __align__(16) unsigned short sK[64][40];
    __shared__ __align__(16) unsigned short sVT[32][72];
    __shared__ float sPE[225];
    unsigned short* sP = &sX[0][0];

    const int tid  = threadIdx.x;
    const int lane = tid & 63;
    const int wv   = tid >> 6;
    const int ln   = lane & 15;
    const int lg   = lane >> 4;

    const int h   = blockIdx.x & 7;
    const int wid = blockIdx.x >> 3;
    const int blw = wid >> 6;
    const int whr = (wid >> 3) & 7;
    const int wwc = wid & 7;
    const int tok_base = blw * 4096 + whr * 512 + wwc * 8;

    if (tid < 225) sPE[tid] = pe[tid];

    #pragma unroll
    for (int it = 0; it < 16; ++it) {
        int g = tid + (it << 8);
        int row = g >> 6, f4 = g & 63;
        int tok = tok_base + ((row >> 3) << 6) + (row & 7);
        float4 v = *reinterpret_cast<const float4*>(x + (size_t)tok * 256 + f4 * 4);
        ushort4 u;
        u.x = f2bf(v.x); u.y = f2bf(v.y); u.z = f2bf(v.z); u.w = f2bf(v.w);
        *reinterpret_cast<ushort4*>(&sX[row][f4 << 2]) = u;
    }

    auto stage_w = [&](int kc) {
        #pragma unroll
        for (int it = 0; it < 8; ++it) {
            int g = tid + (it << 8);
            int k = g >> 5, c = g & 31;
            if (c < 24) {
                int m = c >> 3, f4 = c & 7;
                float4 v = *reinterpret_cast<const float4*>(
                    w_qkv + (size_t)(kc * 64 + k) * 768 + m * 256 + h * 32 + f4 * 4);
                float vals[4] = {v.x, v.y, v.z, v.w};
                int n0 = m * 32 + f4 * 4;
                #pragma unroll
                for (int e0 = 0; e0 < 4; ++e0) {
                    int e = (e0 + lane) & 3;
                    sW[n0 + e][k] = f2bf(vals[e]);
                }
            }
        }
    };

    stage_w(0);
    __syncthreads();

    f32x4 acc[6];
    #pragma unroll
    for (int nt = 0; nt < 6; ++nt) acc[nt] = (f32x4)(0.f);

    for (int kc = 0; kc < 4; ++kc) {
        #pragma unroll
        for (int ks = 0; ks < 2; ++ks) {
            bf16x8 a = ldsFrag(&sX[wv * 16 + ln][kc * 64 + ks * 32 + lg * 8]);
            #pragma unroll
            for (int nt = 0; nt < 6; ++nt) {
                bf16x8 b = ldsFrag(&sW[nt * 16 + ln][ks * 32 + lg * 8]);
                acc[nt] = __builtin_amdgcn_mfma_f32_16x16x32_bf16(a, b, acc[nt], 0, 0, 0);
            }
        }
        if (kc < 3) { __syncthreads(); stage_w(kc + 1); __syncthreads(); }
    }

    #pragma unroll
    for (int nt = 0; nt < 4; ++nt)
        #pragma unroll
        for (int r = 0; r < 4; ++r) {
            int row = wv * 16 + lg * 4 + r;
            unsigned short bv = f2bf(acc[nt][r]);
            if (nt < 2) sQ[row][nt * 16 + ln] = bv;
            else        sK[row][(nt - 2) * 16 + ln] = bv;
        }
    #pragma unroll
    for (int nt = 4; nt < 6; ++nt) {
        ushort4 pv;
        pv.x = f2bf(acc[nt][0]); pv.y = f2bf(acc[nt][1]);
        pv.z = f2bf(acc[nt][2]); pv.w = f2bf(acc[nt][3]);
        *reinterpret_cast<ushort4*>(&sVT[(nt - 4) * 16 + ln][wv * 16 + lg * 4]) = pv;
    }
    __syncthreads();

    const f32x4 zero = (f32x4)(0.f);
    bf16x8 qf = ldsFrag(&sQ[wv * 16 + ln][lg * 8]);
    f32x4 st[4];
    #pragma unroll
    for (int mt = 0; mt < 4; ++mt) {
        bf16x8 kf = ldsFrag(&sK[mt * 16 + ln][lg * 8]);
        st[mt] = __builtin_amdgcn_mfma_f32_16x16x32_bf16(kf, qf, zero, 0, 0, 0);
    }

    const int q = wv * 16 + ln;
    const int qr = q >> 3, qc = q & 7;
    const float scale = 0.17677669529663687f;
    float sv[16];
    float mx = -3.0e38f;
    #pragma unroll
    for (int mt = 0; mt < 4; ++mt)
        #pragma unroll
        for (int r = 0; r < 4; ++r) {
            int j = mt * 16 + lg * 4 + r;
            int dy = (j >> 3) - qr + 7;
            int dx = (j & 7) - qc + 7;
            float s = st[mt][r] * scale + sPE[dy * 15 + dx];
            sv[mt * 4 + r] = s;
            mx = fmaxf(mx, s);
        }
    mx = fmaxf(mx, __shfl_xor(mx, 16));
    mx = fmaxf(mx, __shfl_xor(mx, 32));
    float sum = 0.f;
    #pragma unroll
    for (int i = 0; i < 16; ++i) { sv[i] = __expf(sv[i] - mx); sum += sv[i]; }
    sum += __shfl_xor(sum, 16);
    sum += __shfl_xor(sum, 32);
    const float inv = 1.0f / sum;

    unsigned short* sPw = sP + wv * (16 * 72) + ln * 72;
    #pragma unroll
    for (int mt = 0; mt < 4; ++mt) {
        ushort4 pv;
        pv.x = f2bf(sv[mt * 4 + 0] * inv);
        pv.y = f2bf(sv[mt * 4 + 1] * inv);
        pv.z = f2bf(sv[mt * 4 + 2] * inv);
        pv.w = f2bf(sv[mt * 4 + 3] * inv);
        *reinterpret_cast<ushort4*>(sPw + mt * 16 + lg * 4) = pv;
    }

    f32x4 o[2] = {zero, zero};
    #pragma unroll
    for (int ks = 0; ks < 2; ++ks) {
        bf16x8 pf = ldsFrag(sPw + ks * 32 + lg * 8);
        #pragma unroll
        for (int nt = 0; nt < 2; ++nt) {
            bf16x8 vf = ldsFrag(&sVT[nt * 16 + ln][ks * 32 + lg * 8]);
            o[nt] = __builtin_amdgcn_mfma_f32_16x16x32_bf16(pf, vf, o[nt], 0, 0, 0);
        }
    }
    #pragma unroll
    for (int nt = 0; nt < 2; ++nt)
        #pragma unroll
        for (int r = 0; r < 4; ++r) {
            int qi = wv * 16 + lg * 4 + r;
            int tok = tok_base + ((qi >> 3) << 6) + (qi & 7);
            attn_out[(size_t)tok * 256 + h * 32 + nt * 16 + ln] = o[nt][r];
        }
}

__global__ __launch_bounds__(256, 3)
void proj_fb(float* __restrict__ io,
             const float* __restrict__ w_out,
             const float* __restrict__ b_out)
{
    __shared__ __align__(16) unsigned short sA[64][72];
    __shared__ __align__(16) unsigned short sW2[256][72];
    __shared__ float sB[256];

    const int tid  = threadIdx.x;
    const int lane = tid & 63;
    const int wv   = tid >> 6;
    const int ln   = lane & 15;
    const int lg   = lane >> 4;
    const size_t m0 = (size_t)blockIdx.x * 64;

    sB[tid] = b_out[tid];

    f32x4 acc[16];
    #pragma unroll
    for (int nt = 0; nt < 16; ++nt) acc[nt] = (f32x4)(0.f);

    for (int kc = 0; kc < 4; ++kc) {
        if (kc) __syncthreads();
        #pragma unroll
        for (int it = 0; it < 4; ++it) {
            int g = tid + (it << 8);
            int row = g >> 4, f4 = g & 15;
            float4 v = *reinterpret_cast<const float4*>(
                io + (m0 + row) * 256 + kc * 64 + f4 * 4);
            ushort4 u;
            u.x = f2bf(v.x); u.y = f2bf(v.y); u.z = f2bf(v.z); u.w = f2bf(v.w);
            *reinterpret_cast<ushort4*>(&sA[row][f4 << 2]) = u;
        }
        #pragma unroll
        for (int i = 0; i < 16; ++i) {
            int f4 = ln + 16 * (i & 3);
            int kl = 16 * wv + lg + 4 * (i >> 2);
            float4 v = *reinterpret_cast<const float4*>(
                w_out + (size_t)(kc * 64 + kl) * 256 + f4 * 4);
            float vals[4] = {v.x, v.y, v.z, v.w};
            #pragma unroll
            for (int e0 = 0; e0 < 4; ++e0) {
                int e = (e0 + lane) & 3;
                sW2[f4 * 4 + e][kl] = f2bf(vals[e]);
            }
        }
        __syncthreads();

        #pragma unroll
        for (int ks = 0; ks < 2; ++ks) {
            bf16x8 a = ldsFrag(&sA[wv * 16 + ln][ks * 32 + lg * 8]);
            #pragma unroll
            for (int nt = 0; nt < 16; ++nt) {
                bf16x8 b = ldsFrag(&sW2[nt * 16 + ln][ks * 32 + lg * 8]);
                acc[nt] = __builtin_amdgcn_mfma_f32_16x16x32_bf16(a, b, acc[nt], 0, 0, 0);
            }
        }
    }

    #pragma unroll
    for (int nt = 0; nt < 16; ++nt) {
        float bias = sB[nt * 16 + ln];
        #pragma unroll
        for (int r = 0; r < 4; ++r) {
            int row = wv * 16 + lg * 4 + r;
            io[(m0 + row) * 256 + nt * 16 + ln] = acc[nt][r] + bias;
        }
    }
}

extern "C" void kernel_launch(void* const* d_in, const int* in_sizes, int n_in,
                              void* d_out, int out_size, void* d_ws, size_t ws_size,
                              hipStream_t stream) {
    const float* x     = (const float*)d_in[0];
    const float* w_qkv = (const float*)d_in[1];
    const float* w_out = (const float*)d_in[2];
    const float* b_out = (const float*)d_in[3];
    const float* pe    = (const float*)d_in[4];
    (void)in_sizes; (void)n_in; (void)out_size;

    float* out = (float*)d_out;

    if (ws_size >= (size_t)WS_NEED) {
        unsigned short* wsT = (unsigned short*)d_ws;
        float* bias_tab = (float*)((char*)d_ws + 524288);
        prep_kernel<<<dim3(257),  dim3(256), 0, stream>>>(w_qkv, w_out, pe, wsT, bias_tab);
        winattn2   <<<dim3(4096), dim3(256), 0, stream>>>(x, wsT, bias_tab, out);
        proj2      <<<dim3(1024), dim3(256), 0, stream>>>(out, wsT + WOUTT_SHORT_OFF, b_out);
    } else {
        winattn_fb <<<dim3(8192), dim3(256), 0, stream>>>(x, w_qkv, pe, out);
        proj_fb    <<<dim3(1024), dim3(256), 0, stream>>>(out, w_out, b_out);
    }
}

// Round 5
// 132.128 us; speedup vs baseline: 2.4043x; 2.4043x over previous
//
#include <hip/hip_runtime.h>

typedef float f32x4 __attribute__((ext_vector_type(4)));
typedef short bf16x8 __attribute__((ext_vector_type(8)));

// ---------- bf16 helpers (manual RNE, verified rounds 2-4) ----------
__device__ __forceinline__ unsigned short f2bf(float f) {
    union { float f; unsigned int i; } x;
    x.f = f;
    unsigned int i = x.i;
    unsigned int lsb = (i >> 16) & 1u;
    i += 0x7FFFu + lsb;
    return (unsigned short)(i >> 16);
}
__device__ __forceinline__ bf16x8 cvt8(float4 a, float4 b) {
    union { bf16x8 v; unsigned short u[8]; } r;
    r.u[0] = f2bf(a.x); r.u[1] = f2bf(a.y); r.u[2] = f2bf(a.z); r.u[3] = f2bf(a.w);
    r.u[4] = f2bf(b.x); r.u[5] = f2bf(b.y); r.u[6] = f2bf(b.z); r.u[7] = f2bf(b.w);
    return r.v;
}

// ws layout (bytes):
//   0        : WqkvT bf16 [768][256]   (393216 B)
//   393216   : WoutT bf16 [256][256]   (131072 B)
//   524288   : bias_tab f32 [64][64]   (16384 B)
#define WS_NEED 540672
#define WOUTT_SHORT_OFF 196608

// =====================================================================
// Prep: transpose weights to bf16 n-major; expand PE to [q][j] table.
// =====================================================================
__global__ void prep_kernel(const float* __restrict__ wqkv,
                            const float* __restrict__ wout,
                            const float* __restrict__ pe,
                            unsigned short* __restrict__ wsT,
                            float* __restrict__ bias_tab)
{
    const int b = blockIdx.x, tid = threadIdx.x;
    if (b < 256) {
        const int w = tid >> 6, l = tid & 63;
        const int r = b * 4 + w;               // output row (n)
        const float* src;
        unsigned short* dst;
        int stride;
        if (r < 768) { src = wqkv + r; stride = 768; dst = wsT + (size_t)r * 256; }
        else { int n = r - 768; src = wout + n; stride = 256;
               dst = wsT + WOUTT_SHORT_OFF + (size_t)n * 256; }
        ushort4 v;
        v.x = f2bf(src[(size_t)(l * 4 + 0) * stride]);
        v.y = f2bf(src[(size_t)(l * 4 + 1) * stride]);
        v.z = f2bf(src[(size_t)(l * 4 + 2) * stride]);
        v.w = f2bf(src[(size_t)(l * 4 + 3) * stride]);
        *reinterpret_cast<ushort4*>(dst + l * 4) = v;
    } else {
        #pragma unroll
        for (int i = 0; i < 16; ++i) {
            int idx = tid + i * 256;           // q*64 + j
            int q = idx >> 6, j = idx & 63;
            int dy = (j >> 3) - (q >> 3) + 7;
            int dx = (j & 7) - (q & 7) + 7;
            bias_tab[idx] = pe[dy * 15 + dx];
        }
    }
}

// =====================================================================
// winattn3: 2 heads per block, grid 4096, 256 threads (4 waves).
// K-chunked LDS staging (clean copies from prepped bf16 W^T, no
// transpose / no cvt for W; X cvt'd once per chunk). GEMM buffers
// aliased by attention buffers after the QKV phase. LDS 38912 B.
// =====================================================================
__global__ __launch_bounds__(256, 4)
void winattn3(const float* __restrict__ x,
              const unsigned short* __restrict__ wqkvT,
              const float* __restrict__ bias_tab,
              float* __restrict__ out)
{
    __shared__ __align__(16) unsigned char smem[38912];
    typedef unsigned short (*arr72)[72];
    typedef unsigned short (*arr40)[40];
    // GEMM-phase views
    arr72 sXc = reinterpret_cast<arr72>(smem);            // [64][72]
    arr72 sWc = reinterpret_cast<arr72>(smem + 9216);     // [192][72]
    // attn-phase views (alias; valid after post-GEMM barrier)
    arr40 sQ  = reinterpret_cast<arr40>(smem);            // [2*64][40]
    arr40 sK  = reinterpret_cast<arr40>(smem + 10240);    // [2*64][40]
    arr72 sVT = reinterpret_cast<arr72>(smem + 20480);    // [2*32][72]
    arr72 sP  = reinterpret_cast<arr72>(smem + 29696);    // [4*16][72]

    const int tid  = threadIdx.x;
    const int lane = tid & 63;
    const int wv   = tid >> 6;
    const int ln   = lane & 15;
    const int lg   = lane >> 4;

    // XCD swizzle: the 4 blocks of one window land on the same XCD
    const int L   = ((blockIdx.x & 7) << 9) + (blockIdx.x >> 3);
    const int wid = L >> 2;
    const int h0  = (L & 3) << 1;          // head pair h0, h0+1
    const int blw = wid >> 6;
    const int whr = (wid >> 3) & 7;
    const int wwc = wid & 7;
    const int tok_base = blw * 4096 + whr * 512 + wwc * 8;
    // token(i) = tok_base + (i>>3)*64 + (i&7)

    // ---- QKV GEMM over 4 K-chunks of 64 ----
    f32x4 acc[12];
    #pragma unroll
    for (int i = 0; i < 12; ++i) acc[i] = (f32x4)(0.f);

    for (int kc = 0; kc < 4; ++kc) {
        if (kc) __syncthreads();           // prev chunk reads done

        // stage X chunk: 64 rows x 64 f32 -> bf16 (512 x 16B units)
        #pragma unroll
        for (int it = 0; it < 2; ++it) {
            int idx = tid + (it << 8);
            int row = idx >> 3, c8 = idx & 7;
            int tok = tok_base + ((row >> 3) << 6) + (row & 7);
            const float* p = x + (size_t)tok * 256 + kc * 64 + c8 * 8;
            float4 a = *reinterpret_cast<const float4*>(p);
            float4 b = *reinterpret_cast<const float4*>(p + 4);
            *reinterpret_cast<bf16x8*>(&sXc[row][c8 * 8]) = cvt8(a, b);
        }
        // stage W^T chunk: 192 n-rows x 64 k, straight bf16 copy
        #pragma unroll
        for (int it = 0; it < 6; ++it) {
            int idx = tid + (it << 8);         // 0..1535
            int r = idx >> 3, c8 = idx & 7;
            int g = r >> 5, sub = r & 31;      // g: (q,h0)(q,h1)(k,h0)(k,h1)(v,h0)(v,h1)
            int n = (g >> 1) * 256 + (h0 + (g & 1)) * 32 + sub;
            *reinterpret_cast<bf16x8*>(&sWc[r][c8 * 8]) =
                *reinterpret_cast<const bf16x8*>(
                    wqkvT + (size_t)n * 256 + kc * 64 + c8 * 8);
        }
        __syncthreads();

        #pragma unroll
        for (int ks = 0; ks < 2; ++ks) {
            bf16x8 a = *reinterpret_cast<const bf16x8*>(
                &sXc[wv * 16 + ln][ks * 32 + lg * 8]);
            #pragma unroll
            for (int m = 0; m < 3; ++m)
                #pragma unroll
                for (int hp = 0; hp < 2; ++hp)
                    #pragma unroll
                    for (int hf = 0; hf < 2; ++hf) {
                        int r = (m * 2 + hp) * 32 + hf * 16 + ln;
                        bf16x8 b = *reinterpret_cast<const bf16x8*>(
                            &sWc[r][ks * 32 + lg * 8]);
                        acc[hp * 6 + m * 2 + hf] =
                            __builtin_amdgcn_mfma_f32_16x16x32_bf16(
                                a, b, acc[hp * 6 + m * 2 + hf], 0, 0, 0);
                    }
        }
    }
    __syncthreads();   // last MFMA reads done before alias overwrite

    // ---- epilogue: Q(scaled),K -> [tok][ch]; V -> V^T[ch][tok] ----
    const float scale = 0.17677669529663687f;
    #pragma unroll
    for (int hp = 0; hp < 2; ++hp) {
        #pragma unroll
        for (int j = 0; j < 2; ++j)
            #pragma unroll
            for (int r = 0; r < 4; ++r)
                sQ[hp * 64 + wv * 16 + lg * 4 + r][j * 16 + ln] =
                    f2bf(acc[hp * 6 + j][r] * scale);
        #pragma unroll
        for (int j = 2; j < 4; ++j)
            #pragma unroll
            for (int r = 0; r < 4; ++r)
                sK[hp * 64 + wv * 16 + lg * 4 + r][(j - 2) * 16 + ln] =
                    f2bf(acc[hp * 6 + j][r]);
        #pragma unroll
        for (int j = 4; j < 6; ++j) {
            ushort4 pv;
            pv.x = f2bf(acc[hp * 6 + j][0]); pv.y = f2bf(acc[hp * 6 + j][1]);
            pv.z = f2bf(acc[hp * 6 + j][2]); pv.w = f2bf(acc[hp * 6 + j][3]);
            *reinterpret_cast<ushort4*>(
                &sVT[hp * 32 + (j - 4) * 16 + ln][wv * 16 + lg * 4]) = pv;
        }
    }
    __syncthreads();

    // ---- attention: wave wv owns q-tile wv, loops over both heads ----
    const int q = wv * 16 + ln;
    #pragma unroll
    for (int hp = 0; hp < 2; ++hp) {
        bf16x8 qf = *reinterpret_cast<const bf16x8*>(&sQ[hp * 64 + q][lg * 8]);
        f32x4 st[4];
        #pragma unroll
        for (int mt = 0; mt < 4; ++mt) {
            bf16x8 kf = *reinterpret_cast<const bf16x8*>(
                &sK[hp * 64 + mt * 16 + ln][lg * 8]);
            st[mt] = __builtin_amdgcn_mfma_f32_16x16x32_bf16(
                kf, qf, (f32x4)(0.f), 0, 0, 0);
        }

        float sv[16];
        float mx = -3.0e38f;
        #pragma unroll
        for (int mt = 0; mt < 4; ++mt) {
            float4 bt = *reinterpret_cast<const float4*>(
                &bias_tab[q * 64 + mt * 16 + lg * 4]);
            float b4[4] = {bt.x, bt.y, bt.z, bt.w};
            #pragma unroll
            for (int r = 0; r < 4; ++r) {
                float s = st[mt][r] + b4[r];
                sv[mt * 4 + r] = s;
                mx = fmaxf(mx, s);
            }
        }
        mx = fmaxf(mx, __shfl_xor(mx, 16));
        mx = fmaxf(mx, __shfl_xor(mx, 32));
        float sum = 0.f;
        #pragma unroll
        for (int i = 0; i < 16; ++i) { sv[i] = __expf(sv[i] - mx); sum += sv[i]; }
        sum += __shfl_xor(sum, 16);
        sum += __shfl_xor(sum, 32);
        const float inv = 1.0f / sum;

        #pragma unroll
        for (int mt = 0; mt < 4; ++mt) {
            ushort4 pv;
            pv.x = f2bf(sv[mt * 4 + 0] * inv);
            pv.y = f2bf(sv[mt * 4 + 1] * inv);
            pv.z = f2bf(sv[mt * 4 + 2] * inv);
            pv.w = f2bf(sv[mt * 4 + 3] * inv);
            *reinterpret_cast<ushort4*>(&sP[wv * 16 + ln][mt * 16 + lg * 4]) = pv;
        }

        f32x4 o[2] = {(f32x4)(0.f), (f32x4)(0.f)};
        #pragma unroll
        for (int ks = 0; ks < 2; ++ks) {
            bf16x8 pf = *reinterpret_cast<const bf16x8*>(
                &sP[wv * 16 + ln][ks * 32 + lg * 8]);
            #pragma unroll
            for (int nt = 0; nt < 2; ++nt) {
                bf16x8 vf = *reinterpret_cast<const bf16x8*>(
                    &sVT[hp * 32 + nt * 16 + ln][ks * 32 + lg * 8]);
                o[nt] = __builtin_amdgcn_mfma_f32_16x16x32_bf16(pf, vf, o[nt], 0, 0, 0);
            }
        }

        #pragma unroll
        for (int nt = 0; nt < 2; ++nt) {
            #pragma unroll
            for (int r = 0; r < 4; ++r) {
                int qi  = wv * 16 + lg * 4 + r;
                int tok = tok_base + ((qi >> 3) << 6) + (qi & 7);
                out[(size_t)tok * 256 + (h0 + hp) * 32 + nt * 16 + ln] = o[nt][r];
            }
        }
    }
}

// =====================================================================
// proj3: in-place out = A @ w_out + b_out, K-chunked LDS staging.
// grid 1024, 256 threads (4 waves). LDS 46080 B -> 3 blocks/CU.
// =====================================================================
__global__ __launch_bounds__(256, 3)
void proj3(float* __restrict__ io,
           const unsigned short* __restrict__ woutT,
           const float* __restrict__ b_out)
{
    __shared__ __align__(16) unsigned short sAc[64][72];
    __shared__ __align__(16) unsigned short sWc[256][72];

    const int tid  = threadIdx.x;
    const int lane = tid & 63;
    const int wv   = tid >> 6;
    const int ln   = lane & 15;
    const int lg   = lane >> 4;
    const size_t m0 = (size_t)blockIdx.x * 64;

    f32x4 acc[16];
    #pragma unroll
    for (int nt = 0; nt < 16; ++nt) acc[nt] = (f32x4)(0.f);

    for (int kc = 0; kc < 4; ++kc) {
        if (kc) __syncthreads();

        // stage A chunk (64 rows x 64 f32 -> bf16)
        #pragma unroll
        for (int it = 0; it < 2; ++it) {
            int idx = tid + (it << 8);
            int row = idx >> 3, c8 = idx & 7;
            const float* p = io + (m0 + row) * 256 + kc * 64 + c8 * 8;
            float4 a = *reinterpret_cast<const float4*>(p);
            float4 b = *reinterpret_cast<const float4*>(p + 4);
            *reinterpret_cast<bf16x8*>(&sAc[row][c8 * 8]) = cvt8(a, b);
        }
        // stage W^T chunk (256 n-rows x 64 k), straight bf16 copy
        #pragma unroll
        for (int it = 0; it < 8; ++it) {
            int idx = tid + (it << 8);         // 0..2047
            int r = idx >> 3, c8 = idx & 7;
            *reinterpret_cast<bf16x8*>(&sWc[r][c8 * 8]) =
                *reinterpret_cast<const bf16x8*>(
                    woutT + (size_t)r * 256 + kc * 64 + c8 * 8);
        }
        __syncthreads();

        #pragma unroll
        for (int ks = 0; ks < 2; ++ks) {
            bf16x8 a = *reinterpret_cast<const bf16x8*>(
                &sAc[wv * 16 + ln][ks * 32 + lg * 8]);
            #pragma unroll
            for (int nt = 0; nt < 16; ++nt) {
                bf16x8 b = *reinterpret_cast<const bf16x8*>(
                    &sWc[nt * 16 + ln][ks * 32 + lg * 8]);
                acc[nt] = __builtin_amdgcn_mfma_f32_16x16x32_bf16(a, b, acc[nt], 0, 0, 0);
            }
        }
    }

    // all io reads happened in staging (pre-barrier); safe to overwrite
    #pragma unroll
    for (int nt = 0; nt < 16; ++nt) {
        float bias = b_out[nt * 16 + ln];
        #pragma unroll
        for (int r = 0; r < 4; ++r)
            io[(m0 + wv * 16 + lg * 4 + r) * 256 + nt * 16 + ln] = acc[nt][r] + bias;
    }
}

// =====================================================================
// Fallback (round-3 verified kernels) if ws_size < WS_NEED.
// =====================================================================
__device__ __forceinline__ bf16x8 ldsFrag(const unsigned short* p) {
    return *reinterpret_cast<const bf16x8*>(p);
}

__global__ __launch_bounds__(256, 2)
void winattn_fb(const float* __restrict__ x,
                const float* __restrict__ w_qkv,
                const float* __restrict__ pe,
                float* __restrict__ attn_out)
{
    __shared__ __align__(16) unsigned short sX[64][264];
    __shared__ __align__(16) unsigned short sW[96][72];
    __shared__ __align__(16) unsigned short sQ[64][40];
    __shared__ __align__(16) unsigned short sK[64][40];
    __shared__ __align__(16) unsigned short sVT[32][72];
    __shared__ float sPE[225];
    unsigned short* sP = &sX[0][0];

    const int tid  = threadIdx.x;
    const int lane = tid & 63;
    const int wv   = tid >> 6;
    const int ln   = lane & 15;
    const int lg   = lane >> 4;

    const int h   = blockIdx.x & 7;
    const int wid = blockIdx.x >> 3;
    const int blw = wid >> 6;
    const int whr = (wid >> 3) & 7;
    const int wwc = wid & 7;
    const int tok_base = blw * 4096 + whr * 512 + wwc * 8;

    if (tid < 225) sPE[tid] = pe[tid];

    #pragma unroll
    for (int it = 0; it < 16; ++it) {
        int g = tid + (it << 8);
        int row = g >> 6, f4 = g & 63;
        int tok = tok_base + ((row >> 3) << 6) + (row & 7);
        float4 v = *reinterpret_cast<const float4*>(x + (size_t)tok * 256 + f4 * 4);
        ushort4 u;
        u.x = f2bf(v.x); u.y = f2bf(v.y); u.z = f2bf(v.z); u.w = f2bf(v.w);
        *reinterpret_cast<ushort4*>(&sX[row][f4 << 2]) = u;
    }

    auto stage_w = [&](int kc) {
        #pragma unroll
        for (int it = 0; it < 8; ++it) {
            int g = tid + (it << 8);
            int k = g >> 5, c = g & 31;
            if (c < 24) {
                int m = c >> 3, f4 = c & 7;
                float4 v = *reinterpret_cast<const float4*>(
                    w_qkv + (size_t)(kc * 64 + k) * 768 + m * 256 + h * 32 + f4 * 4);
                float vals[4] = {v.x, v.y, v.z, v.w};
                int n0 = m * 32 + f4 * 4;
                #pragma unroll
                for (int e0 = 0; e0 < 4; ++e0) {
                    int e = (e0 + lane) & 3;
                    sW[n0 + e][k] = f2bf(vals[e]);
                }
            }
        }
    };

    stage_w(0);
    __syncthreads();

    f32x4 acc[6];
    #pragma unroll
    for (int nt = 0; nt < 6; ++nt) acc[nt] = (f32x4)(0.f);

    for (int kc = 0; kc < 4; ++kc) {
        #pragma unroll
        for (int ks = 0; ks < 2; ++ks) {
            bf16x8 a = ldsFrag(&sX[wv * 16 + ln][kc * 64 + ks * 32 + lg * 8]);
            #pragma unroll
            for (int nt = 0; nt < 6; ++nt) {
                bf16x8 b = ldsFrag(&sW[nt * 16 + ln][ks * 32 + lg * 8]);
                acc[nt] = __builtin_amdgcn_mfma_f32_16x16x32_bf16(a, b, acc[nt], 0, 0, 0);
            }
        }
        if (kc < 3) { __syncthreads(); stage_w(kc + 1); __syncthreads(); }
    }

    #pragma unroll
    for (int nt = 0; nt < 4; ++nt)
        #pragma unroll
        for (int r = 0; r < 4; ++r) {
            int row = wv * 16 + lg * 4 + r;
            unsigned short bv = f2bf(acc[nt][r]);
            if (nt < 2) sQ[row][nt * 16 + ln] = bv;
            else        sK[row][(nt - 2) * 16 + ln] = bv;
        }
    #pragma unroll
    for (int nt = 4; nt < 6; ++nt) {
        ushort4 pv;
        pv.x = f2bf(acc[nt][0]); pv.y = f2bf(acc[nt][1]);
        pv.z = f2bf(acc[nt][2]); pv.w = f2bf(acc[nt][3]);
        *reinterpret_cast<ushort4*>(&sVT[(nt - 4) * 16 + ln][wv * 16 + lg * 4]) = pv;
    }
    __syncthreads();

    const f32x4 zero = (f32x4)(0.f);
    bf16x8 qf = ldsFrag(&sQ[wv * 16 + ln][lg * 8]);
    f32x4 st[4];
    #pragma unroll
    for (int mt = 0; mt < 4; ++mt) {
        bf16x8 kf = ldsFrag(&sK[mt * 16 + ln][lg * 8]);
        st[mt] = __builtin_amdgcn_mfma_f32_16x16x32_bf16(kf, qf, zero, 0, 0, 0);
    }

    const int q = wv * 16 + ln;
    const int qr = q >> 3, qc = q & 7;
    const float scale = 0.17677669529663687f;
    float sv[16];
    float mx = -3.0e38f;
    #pragma unroll
    for (int mt = 0; mt < 4; ++mt)
        #pragma unroll
        for (int r = 0; r < 4; ++r) {
            int j = mt * 16 + lg * 4 + r;
            int dy = (j >> 3) - qr + 7;
            int dx = (j & 7) - qc + 7;
            float s = st[mt][r] * scale + sPE[dy * 15 + dx];
            sv[mt * 4 + r] = s;
            mx = fmaxf(mx, s);
        }
    mx = fmaxf(mx, __shfl_xor(mx, 16));
    mx = fmaxf(mx, __shfl_xor(mx, 32));
    float sum = 0.f;
    #pragma unroll
    for (int i = 0; i < 16; ++i) { sv[i] = __expf(sv[i] - mx); sum += sv[i]; }
    sum += __shfl_xor(sum, 16);
    sum += __shfl_xor(sum, 32);
    const float inv = 1.0f / sum;

    unsigned short* sPw = sP + wv * (16 * 72) + ln * 72;
    #pragma unroll
    for (int mt = 0; mt < 4; ++mt) {
        ushort4 pv;
        pv.x = f2bf(sv[mt * 4 + 0] * inv);
        pv.y = f2bf(sv[mt * 4 + 1] * inv);
        pv.z = f2bf(sv[mt * 4 + 2] * inv);
        pv.w = f2bf(sv[mt * 4 + 3] * inv);
        *reinterpret_cast<ushort4*>(sPw + mt * 16 + lg * 4) = pv;
    }

    f32x4 o[2] = {zero, zero};
    #pragma unroll
    for (int ks = 0; ks < 2; ++ks) {
        bf16x8 pf = ldsFrag(sPw + ks * 32 + lg * 8);
        #pragma unroll
        for (int nt = 0; nt < 2; ++nt) {
            bf16x8 vf = ldsFrag(&sVT[nt * 16 + ln][ks * 32 + lg * 8]);
            o[nt] = __builtin_amdgcn_mfma_f32_16x16x32_bf16(pf, vf, o[nt], 0, 0, 0);
        }
    }
    #pragma unroll
    for (int nt = 0; nt < 2; ++nt)
        #pragma unroll
        for (int r = 0; r < 4; ++r) {
            int qi = wv * 16 + lg * 4 + r;
            int tok = tok_base + ((qi >> 3) << 6) + (qi & 7);
            attn_out[(size_t)tok * 256 + h * 32 + nt * 16 + ln] = o[nt][r];
        }
}

__global__ __launch_bounds__(256, 3)
void proj_fb(float* __restrict__ io,
             const float* __restrict__ w_out,
             const float* __restrict__ b_out)
{
    __shared__ __align__(16) unsigned short sA[64][72];
    __shared__ __align__(16) unsigned short sW2[256][72];
    __shared__ float sB[256];

    const int tid  = threadIdx.x;
    const int lane = tid & 63;
    const int wv   = tid >> 6;
    const int ln   = lane & 15;
    const int lg   = lane >> 4;
    const size_t m0 = (size_t)blockIdx.x * 64;

    sB[tid] = b_out[tid];

    f32x4 acc[16];
    #pragma unroll
    for (int nt = 0; nt < 16; ++nt) acc[nt] = (f32x4)(0.f);

    for (int kc = 0; kc < 4; ++kc) {
        if (kc) __syncthreads();
        #pragma unroll
        for (int it = 0; it < 4; ++it) {
            int g = tid + (it << 8);
            int row = g >> 4, f4 = g & 15;
            float4 v = *reinterpret_cast<const float4*>(
                io + (m0 + row) * 256 + kc * 64 + f4 * 4);
            ushort4 u;
            u.x = f2bf(v.x); u.y = f2bf(v.y); u.z = f2bf(v.z); u.w = f2bf(v.w);
            *reinterpret_cast<ushort4*>(&sA[row][f4 << 2]) = u;
        }
        #pragma unroll
        for (int i = 0; i < 16; ++i) {
            int f4 = ln + 16 * (i & 3);
            int kl = 16 * wv + lg + 4 * (i >> 2);
            float4 v = *reinterpret_cast<const float4*>(
                w_out + (size_t)(kc * 64 + kl) * 256 + f4 * 4);
            float vals[4] = {v.x, v.y, v.z, v.w};
            #pragma unroll
            for (int e0 = 0; e0 < 4; ++e0) {
                int e = (e0 + lane) & 3;
                sW2[f4 * 4 + e][kl] = f2bf(vals[e]);
            }
        }
        __syncthreads();

        #pragma unroll
        for (int ks = 0; ks < 2; ++ks) {
            bf16x8 a = ldsFrag(&sA[wv * 16 + ln][ks * 32 + lg * 8]);
            #pragma unroll
            for (int nt = 0; nt < 16; ++nt) {
                bf16x8 b = ldsFrag(&sW2[nt * 16 + ln][ks * 32 + lg * 8]);
                acc[nt] = __builtin_amdgcn_mfma_f32_16x16x32_bf16(a, b, acc[nt], 0, 0, 0);
            }
        }
    }

    #pragma unroll
    for (int nt = 0; nt < 16; ++nt) {
        float bias = sB[nt * 16 + ln];
        #pragma unroll
        for (int r = 0; r < 4; ++r) {
            int row = wv * 16 + lg * 4 + r;
            io[(m0 + row) * 256 + nt * 16 + ln] = acc[nt][r] + bias;
        }
    }
}

extern "C" void kernel_launch(void* const* d_in, const int* in_sizes, int n_in,
                              void* d_out, int out_size, void* d_ws, size_t ws_size,
                              hipStream_t stream) {
    const float* x     = (const float*)d_in[0];
    const float* w_qkv = (const float*)d_in[1];
    const float* w_out = (const float*)d_in[2];
    const float* b_out = (const float*)d_in[3];
    const float* pe    = (const float*)d_in[4];
    (void)in_sizes; (void)n_in; (void)out_size;

    float* out = (float*)d_out;

    if (ws_size >= (size_t)WS_NEED) {
        unsigned short* wsT = (unsigned short*)d_ws;
        float* bias_tab = (float*)((char*)d_ws + 524288);
        prep_kernel<<<dim3(257),  dim3(256), 0, stream>>>(w_qkv, w_out, pe, wsT, bias_tab);
        winattn3   <<<dim3(4096), dim3(256), 0, stream>>>(x, wsT, bias_tab, out);
        proj3      <<<dim3(1024), dim3(256), 0, stream>>>(out, wsT + WOUTT_SHORT_OFF, b_out);
    } else {
        winattn_fb <<<dim3(8192), dim3(256), 0, stream>>>(x, w_qkv, pe, out);
        proj_fb    <<<dim3(1024), dim3(256), 0, stream>>>(out, w_out, b_out);
    }
}